// Round 6
// baseline (236701.514 us; speedup 1.0000x reference)
//
#include <hip/hip_runtime.h>
#include <math.h>

#define T 512
#define B 128
#define E 256
#define H 256
#define G 1024   // 4H
#define DA 25
#define HEADS 5
#define NEGINF (-1e30f)

// ---------------- workspace layout (bytes) ----------------
static constexpr size_t WBT_OFF  = 0;           // [2][128 k2][256 j][8] ushort (bf16 W_hh^T) 1,048,576
static constexpr size_t WS1T_OFF = 2097152;     // [512][25] f32                  51,200
static constexpr size_t PX_OFF   = 2148352;     // [2][64][128][1024] f32     67,108,864
static constexpr size_t HC_OFF   = 69257216;    // [128][512][512] f32       134,217,728
static constexpr size_t HBUF_OFF = 203474944;   // [2][64 bt][256 j] float2      262,144
static constexpr size_t CST_OFF  = 203737088;   // [2][128][256] f32 c-state     262,144
static constexpr size_t A_OFF    = 203999232;   // [128][5][512] f32           1,310,720
static constexpr size_t PART_OFF = 205309952;   // [128] f32                         512

__device__ __forceinline__ float sigmoidf_(float x) { return 1.f / (1.f + expf(-x)); }
__device__ __forceinline__ float blo_(unsigned u) { return __uint_as_float(u << 16); }
__device__ __forceinline__ float bhi_(unsigned u) { return __uint_as_float(u & 0xffff0000u); }

__device__ __forceinline__ unsigned short f2bf_(float f) {   // RNE bf16
    unsigned u = __float_as_uint(f);
    unsigned r = (u + 0x7fffu + ((u >> 16) & 1u)) >> 16;
    return (unsigned short)r;
}

// ---------------- prep: pack W_hh (bf16, k-pair/gate interleaved) + W_s1^T --
// wbt layout: [(d*128 + k2)*256 + j]*8 + ke*4 + gate  (ushort)
__global__ __launch_bounds__(256) void prep_kernel(const float* __restrict__ Whf,
                                                   const float* __restrict__ Whb,
                                                   const float* __restrict__ Ws1,
                                                   unsigned short* __restrict__ wbt,
                                                   float* __restrict__ ws1t) {
    int idx = blockIdx.x * 256 + threadIdx.x;
    if (idx < 2 * G * H) {
        int d = idx >> 18;
        int rem = idx & 262143;
        int r = rem >> 8;                        // gate row 0..1023
        int k = rem & 255;                       // h index
        const float* W = d ? Whb : Whf;
        int gate = r >> 8, j = r & 255;
        int k2 = k >> 1, ke = k & 1;
        wbt[(((size_t)d * 128 + k2) * 256 + j) * 8 + ke * 4 + gate] = f2bf_(W[(size_t)r * H + k]);
    }
    if (idx < DA * 512) {
        int r = idx / 512, k = idx % 512;
        ws1t[k * DA + r] = Ws1[idx];
    }
}

// ---------------- input projection for one 64-step chunk ----------------
// grid (16 gtiles, 128 b, 2 dir), block 256
__global__ __launch_bounds__(256) void proj_kernel(const int* __restrict__ word_ids,
                                                   const int* __restrict__ lengths,
                                                   const float* __restrict__ emb,
                                                   const float* __restrict__ Wf,
                                                   const float* __restrict__ Wb,
                                                   const float* __restrict__ bf,
                                                   const float* __restrict__ bb,
                                                   float* __restrict__ pxc, int chunk) {
    int g0 = blockIdx.x * 64;
    int b  = blockIdx.y;
    int d  = blockIdx.z;
    int len = lengths[b];
    int t0 = chunk * 64;
    if (t0 >= len) return;
    const float* Wih  = d ? Wb : Wf;
    const float* bias = d ? bb : bf;

    __shared__ int   wid[64];
    __shared__ float As[64][17];   // [m][kk], k-minor, padded
    __shared__ float Bs[64][17];

    int tid = threadIdx.x;
    if (tid < 64) {
        int t = t0 + tid;
        int src;
        if (d == 0) src = t;
        else { src = len - 1 - t; if (src < 0) src = 0; }
        wid[tid] = word_ids[b * T + src];
    }
    __syncthreads();

    int tx = tid & 15, ty = tid >> 4;   // compute mapping
    int kk = tid & 15, r0 = tid >> 4;   // load mapping
    float acc[4][4];
    #pragma unroll
    for (int i = 0; i < 4; i++)
        #pragma unroll
        for (int j = 0; j < 4; j++) acc[i][j] = 0.f;

    for (int k0 = 0; k0 < E; k0 += 16) {
        #pragma unroll
        for (int i = 0; i < 4; i++) {
            int m = r0 + 16 * i;
            As[m][kk] = emb[(size_t)wid[m] * E + k0 + kk];
            Bs[m][kk] = Wih[(size_t)(g0 + m) * E + k0 + kk];
        }
        __syncthreads();
        #pragma unroll
        for (int kq = 0; kq < 16; kq++) {
            float a[4], bv[4];
            #pragma unroll
            for (int i = 0; i < 4; i++) a[i] = As[ty * 4 + i][kq];
            #pragma unroll
            for (int j = 0; j < 4; j++) bv[j] = Bs[tx * 4 + j][kq];
            #pragma unroll
            for (int i = 0; i < 4; i++)
                #pragma unroll
                for (int j = 0; j < 4; j++) acc[i][j] += a[i] * bv[j];
        }
        __syncthreads();
    }
    #pragma unroll
    for (int i = 0; i < 4; i++) {
        int m = ty * 4 + i;
        #pragma unroll
        for (int j = 0; j < 4; j++) {
            int n = tx * 4 + j;
            pxc[((size_t)(d * 64 + m) * B + b) * G + g0 + n] = acc[i][j] + bias[g0 + n];
        }
    }
}

// 8 k-pairs of FMAs against batch array WARR, h from hcur[KBASE..KBASE+7]
#define DO8(WARR, KBASE)                                              \
    _Pragma("unroll")                                                 \
    for (int u = 0; u < 8; u++) {                                     \
        uint4 wv = WARR[u];                                           \
        float4 hv = hcur[(KBASE) + u];                                \
        float w0e = blo_(wv.x), w1e = bhi_(wv.x);                     \
        float w2e = blo_(wv.y), w3e = bhi_(wv.y);                     \
        float w0o = blo_(wv.z), w1o = bhi_(wv.z);                     \
        float w2o = blo_(wv.w), w3o = bhi_(wv.w);                     \
        a00 = fmaf(w0e, hv.x, a00); a01 = fmaf(w0e, hv.y, a01);       \
        a10 = fmaf(w1e, hv.x, a10); a11 = fmaf(w1e, hv.y, a11);       \
        a20 = fmaf(w2e, hv.x, a20); a21 = fmaf(w2e, hv.y, a21);       \
        a30 = fmaf(w3e, hv.x, a30); a31 = fmaf(w3e, hv.y, a31);       \
        a00 = fmaf(w0o, hv.z, a00); a01 = fmaf(w0o, hv.w, a01);       \
        a10 = fmaf(w1o, hv.z, a10); a11 = fmaf(w1o, hv.w, a11);       \
        a20 = fmaf(w2o, hv.z, a20); a21 = fmaf(w2o, hv.w, a21);       \
        a30 = fmaf(w3o, hv.z, a30); a31 = fmaf(w3o, hv.w, a31);       \
    }

// ---------------- LSTM recurrence, one 64-step chunk, NO cross-block sync ---
// grid (64 btiles, 2 dir); block 256. Block owns 2 samples (b0, b0+1).
// Thread tid owns hidden col j=tid: all 4 gates x 2 samples stay local.
// W_hh^T bf16 streamed from L2 with explicit 8-deep double-buffered prefetch
// (8 outstanding 16B loads/thread) + px prefetched one step ahead.
__global__ __launch_bounds__(256) void lstm2_kernel(const int* __restrict__ lengths,
                                                    const unsigned short* __restrict__ wbt,
                                                    const float* __restrict__ pxc,
                                                    float* __restrict__ hc_out,
                                                    float* __restrict__ hbuf,
                                                    float* __restrict__ cstate,
                                                    int chunk) {
    int bt = blockIdx.x;
    int d  = blockIdx.y;
    int b0 = bt * 2;
    int tid = threadIdx.x;

    int len0 = lengths[b0], len1 = lengths[b0 + 1];
    int maxlen = max(len0, len1);
    int t0 = chunk * 64;
    if (t0 >= maxlen) return;
    int tend = min(t0 + 64, maxlen);

    __shared__ float2 hping[2][256];   // [buf][k] = h[k] for samples {b0, b0+1}

    float2* hbufg = (float2*)hbuf + ((size_t)d * 64 + bt) * 256;

    float c0, c1;
    int cur = 0;
    if (chunk == 0) {
        c0 = 0.f; c1 = 0.f;
        hping[0][tid] = make_float2(0.f, 0.f);
    } else {
        c0 = cstate[((size_t)d * B + b0) * H + tid];
        c1 = cstate[((size_t)d * B + b0 + 1) * H + tid];
        hping[0][tid] = hbufg[tid];
    }
    __syncthreads();

    const uint4* wp  = (const uint4*)wbt + (size_t)d * 128 * 256 + tid;  // [k2][j=tid]
    const float* pxd = pxc + (size_t)d * 64 * B * G;

    // preload px for first step
    float pc0, pc1, pc2, pc3, pc4, pc5, pc6, pc7;
    {
        const float* pxs = pxd + ((size_t)(t0 - chunk * 64) * B + b0) * G;
        pc0 = pxs[tid];       pc1 = pxs[G + tid];
        pc2 = pxs[256 + tid]; pc3 = pxs[G + 256 + tid];
        pc4 = pxs[512 + tid]; pc5 = pxs[G + 512 + tid];
        pc6 = pxs[768 + tid]; pc7 = pxs[G + 768 + tid];
    }

    for (int t = t0; t < tend; t++) {
        int s = t - t0;
        float a00 = pc0, a01 = pc1;
        float a10 = pc2, a11 = pc3;
        float a20 = pc4, a21 = pc5;
        float a30 = pc6, a31 = pc7;

        // prefetch px for next step (clamped; garbage ok, overwritten checks by length)
        int sn = (s + 1 < 64) ? (s + 1) : s;
        const float* pxn = pxd + ((size_t)sn * B + b0) * G;
        float n0 = pxn[tid],       n1 = pxn[G + tid];
        float n2 = pxn[256 + tid], n3 = pxn[G + 256 + tid];
        float n4 = pxn[512 + tid], n5 = pxn[G + 512 + tid];
        float n6 = pxn[768 + tid], n7 = pxn[G + 768 + tid];

        const float4* hcur = (const float4*)hping[cur];
        uint4 wv0[8], wv1[8];
        #pragma unroll
        for (int u = 0; u < 8; u++) wv0[u] = wp[u * 256];
        #pragma unroll
        for (int k16 = 0; k16 < 8; k16++) {
            #pragma unroll
            for (int u = 0; u < 8; u++) wv1[u] = wp[((2 * k16 + 1) * 8 + u) * 256];
            DO8(wv0, k16 * 16);
            if (k16 < 7) {
                #pragma unroll
                for (int u = 0; u < 8; u++) wv0[u] = wp[((2 * k16 + 2) * 8 + u) * 256];
            }
            DO8(wv1, k16 * 16 + 8);
        }

        float i0 = sigmoidf_(a00), f0 = sigmoidf_(a10), o0 = sigmoidf_(a30);
        c0 = f0 * c0 + i0 * tanhf(a20);
        float h0 = o0 * tanhf(c0);
        float i1 = sigmoidf_(a01), f1 = sigmoidf_(a11), o1 = sigmoidf_(a31);
        c1 = f1 * c1 + i1 * tanhf(a21);
        float h1 = o1 * tanhf(c1);

        hping[cur ^ 1][tid] = make_float2(h0, h1);
        if (t < len0) {
            int pos = d ? (len0 - 1 - t) : t;
            hc_out[((size_t)b0 * T + pos) * (2 * H) + d * H + tid] = h0;
        }
        if (t < len1) {
            int pos = d ? (len1 - 1 - t) : t;
            hc_out[((size_t)(b0 + 1) * T + pos) * (2 * H) + d * H + tid] = h1;
        }
        pc0 = n0; pc1 = n1; pc2 = n2; pc3 = n3;
        pc4 = n4; pc5 = n5; pc6 = n6; pc7 = n7;
        __syncthreads();   // everyone done reading hping[cur] and writing [cur^1]
        cur ^= 1;
    }

    cstate[((size_t)d * B + b0) * H + tid]     = c0;
    cstate[((size_t)d * B + b0 + 1) * H + tid] = c1;
    hbufg[tid] = hping[cur][tid];
}

// ---------------- attention logits (masked) ----------------
__global__ __launch_bounds__(256) void logits_kernel(const int* __restrict__ lengths,
                                                     const float* __restrict__ hc,
                                                     const float* __restrict__ ws1t,
                                                     const float* __restrict__ Ws2,
                                                     float* __restrict__ S) {
    __shared__ float s_w1[512 * DA];
    __shared__ float s_w2[HEADS * DA];
    int b = blockIdx.y, tt = blockIdx.x;
    int tid = threadIdx.x;
    for (int i = tid; i < 512 * DA; i += 256) s_w1[i] = ws1t[i];
    for (int i = tid; i < HEADS * DA; i += 256) s_w2[i] = Ws2[i];
    __syncthreads();

    int len = lengths[b];
    int lane = tid & 63, wave = tid >> 6;
    for (int ti = 0; ti < 16; ti++) {
        int t = tt * 64 + wave * 16 + ti;
        if (t < len) {
            float y[DA];
            #pragma unroll
            for (int r = 0; r < DA; r++) y[r] = 0.f;
            const float* hcp = hc + ((size_t)b * T + t) * (2 * H);
            #pragma unroll
            for (int kk = 0; kk < 8; kk++) {
                int k = lane + kk * 64;
                float v = hcp[k];
                const float* w = s_w1 + k * DA;
                #pragma unroll
                for (int r = 0; r < DA; r++) y[r] += v * w[r];
            }
            #pragma unroll
            for (int r = 0; r < DA; r++) {
                float v = y[r];
                for (int off = 32; off; off >>= 1) v += __shfl_xor(v, off, 64);
                y[r] = tanhf(v);
            }
            if (lane < HEADS) {
                float s = 0.f;
                #pragma unroll
                for (int r = 0; r < DA; r++) s += y[r] * s_w2[lane * DA + r];
                S[((size_t)b * HEADS + lane) * T + t] = s;
            }
        } else {
            if (lane < HEADS) S[((size_t)b * HEADS + lane) * T + t] = NEGINF;
        }
    }
}

// ---------------- masked softmax over T, in place ----------------
__global__ __launch_bounds__(256) void softmax_kernel(float* __restrict__ S) {
    int row = blockIdx.x;
    float* p = S + (size_t)row * T;
    int tid = threadIdx.x;
    int lane = tid & 63, wave = tid >> 6;
    __shared__ float rr[4], ss[4];

    float mx = NEGINF;
    #pragma unroll
    for (int i = 0; i < 2; i++) mx = fmaxf(mx, p[tid + i * 256]);
    for (int off = 32; off; off >>= 1) mx = fmaxf(mx, __shfl_xor(mx, off, 64));
    if (lane == 0) rr[wave] = mx;
    __syncthreads();
    mx = fmaxf(fmaxf(rr[0], rr[1]), fmaxf(rr[2], rr[3]));

    float e[2], sum = 0.f;
    #pragma unroll
    for (int i = 0; i < 2; i++) { e[i] = expf(p[tid + i * 256] - mx); sum += e[i]; }
    for (int off = 32; off; off >>= 1) sum += __shfl_xor(sum, off, 64);
    if (lane == 0) ss[wave] = sum;
    __syncthreads();
    sum = ss[0] + ss[1] + ss[2] + ss[3];
    float inv = 1.f / sum;
    #pragma unroll
    for (int i = 0; i < 2; i++) p[tid + i * 256] = e[i] * inv;
}

// ---------------- M = A @ Hc -> sentence embeddings (d_out) ----------------
__global__ __launch_bounds__(256) void attnM_kernel(const int* __restrict__ lengths,
                                                    const float* __restrict__ A,
                                                    const float* __restrict__ hc,
                                                    float* __restrict__ out) {
    int b = blockIdx.x, tid = threadIdx.x;
    int len = lengths[b];
    const float* Ab  = A + (size_t)b * HEADS * T;
    const float* hcb = hc + (size_t)b * T * (2 * H);
    float acc[HEADS][2];
    #pragma unroll
    for (int h = 0; h < HEADS; h++) { acc[h][0] = 0.f; acc[h][1] = 0.f; }
    for (int t = 0; t < len; t++) {
        float v0 = hcb[(size_t)t * (2 * H) + tid];
        float v1 = hcb[(size_t)t * (2 * H) + H + tid];
        #pragma unroll
        for (int h = 0; h < HEADS; h++) {
            float a = Ab[h * T + t];
            acc[h][0] += a * v0;
            acc[h][1] += a * v1;
        }
    }
    #pragma unroll
    for (int h = 0; h < HEADS; h++) {
        out[(size_t)b * (HEADS * 2 * H) + h * (2 * H) + tid]     = acc[h][0];
        out[(size_t)b * (HEADS * 2 * H) + h * (2 * H) + H + tid] = acc[h][1];
    }
}

// ---------------- penalization ----------------
__global__ __launch_bounds__(256) void penal_kernel(const float* __restrict__ A,
                                                    float* __restrict__ part) {
    int b = blockIdx.x, tid = threadIdx.x;
    const float* Ab = A + (size_t)b * HEADS * T;
    float p[10];
    #pragma unroll
    for (int i = 0; i < 10; i++) p[i] = 0.f;
    for (int t = tid; t < T; t += 256) {
        float a0 = Ab[t], a1 = Ab[T + t], a2 = Ab[2 * T + t], a3 = Ab[3 * T + t], a4 = Ab[4 * T + t];
        p[0] += a0 * a1; p[1] += a0 * a2; p[2] += a0 * a3; p[3] += a0 * a4;
        p[4] += a1 * a2; p[5] += a1 * a3; p[6] += a1 * a4;
        p[7] += a2 * a3; p[8] += a2 * a4; p[9] += a3 * a4;
    }
    __shared__ float red[10][4];
    int lane = tid & 63, wave = tid >> 6;
    #pragma unroll
    for (int i = 0; i < 10; i++) {
        float v = p[i];
        for (int off = 32; off; off >>= 1) v += __shfl_xor(v, off, 64);
        if (lane == 0) red[i][wave] = v;
    }
    __syncthreads();
    if (tid == 0) {
        float s = 0.f;
        #pragma unroll
        for (int i = 0; i < 10; i++) {
            float P = red[i][0] + red[i][1] + red[i][2] + red[i][3];
            s += 2.f * P * P;
        }
        part[b] = s;
    }
}

__global__ __launch_bounds__(128) void final_kernel(const float* __restrict__ part,
                                                    float* __restrict__ out) {
    int tid = threadIdx.x;
    float v = part[tid];
    for (int off = 32; off; off >>= 1) v += __shfl_xor(v, off, 64);
    __shared__ float r2[2];
    if ((tid & 63) == 0) r2[tid >> 6] = v;
    __syncthreads();
    if (tid == 0) out[(size_t)B * HEADS * 2 * H] = (r2[0] + r2[1]) * (1.f / (float)B);
}

// ---------------- host launcher ----------------
extern "C" void kernel_launch(void* const* d_in, const int* in_sizes, int n_in,
                              void* d_out, int out_size, void* d_ws, size_t ws_size,
                              hipStream_t stream) {
    const int*   word_ids = (const int*)d_in[0];
    const int*   lengths  = (const int*)d_in[1];
    const float* emb      = (const float*)d_in[2];
    const float* W_ih_f   = (const float*)d_in[3];
    const float* W_hh_f   = (const float*)d_in[4];
    const float* b_f      = (const float*)d_in[5];
    const float* W_ih_b   = (const float*)d_in[6];
    const float* W_hh_b   = (const float*)d_in[7];
    const float* b_b      = (const float*)d_in[8];
    const float* W_s1     = (const float*)d_in[9];
    const float* W_s2     = (const float*)d_in[10];
    float* out = (float*)d_out;

    char* ws = (char*)d_ws;
    unsigned short* wbt = (unsigned short*)(ws + WBT_OFF);
    float* ws1t   = (float*)(ws + WS1T_OFF);
    float* pxc    = (float*)(ws + PX_OFF);
    float* hc     = (float*)(ws + HC_OFF);
    float* hbuf   = (float*)(ws + HBUF_OFF);
    float* cstate = (float*)(ws + CST_OFF);
    float* Abuf   = (float*)(ws + A_OFF);
    float* part   = (float*)(ws + PART_OFF);

    prep_kernel<<<2048, 256, 0, stream>>>(W_hh_f, W_hh_b, W_s1, wbt, ws1t);

    for (int c = 0; c < 8; c++) {
        proj_kernel<<<dim3(16, 128, 2), 256, 0, stream>>>(
            word_ids, lengths, emb, W_ih_f, W_ih_b, b_f, b_b, pxc, c);
        lstm2_kernel<<<dim3(64, 2), 256, 0, stream>>>(
            lengths, wbt, pxc, hc, hbuf, cstate, c);
    }

    logits_kernel<<<dim3(8, 128), 256, 0, stream>>>(lengths, hc, ws1t, W_s2, Abuf);
    softmax_kernel<<<B * HEADS, 256, 0, stream>>>(Abuf);
    attnM_kernel<<<B, 256, 0, stream>>>(lengths, Abuf, hc, out);
    penal_kernel<<<B, 256, 0, stream>>>(Abuf, part);
    final_kernel<<<1, 128, 0, stream>>>(part, out);
}

// Round 7
// 4254.675 us; speedup vs baseline: 55.6333x; 55.6333x over previous
//
#include <hip/hip_runtime.h>
#include <math.h>

#define T 512
#define B 128
#define E 256
#define H 256
#define G 1024   // 4H
#define DA 25
#define HEADS 5
#define NEGINF (-1e30f)

// ---------------- workspace layout (bytes) ----------------
static constexpr size_t WBT_OFF  = 0;           // [2][128 k2][256 j][8] ushort (bf16 W_hh^T) 1,048,576
static constexpr size_t WS1T_OFF = 2097152;     // [512][25] f32                  51,200
static constexpr size_t PX_OFF   = 2148352;     // [2][64][128][1024] f32     67,108,864
static constexpr size_t HC_OFF   = 69257216;    // [128][512][512] f32       134,217,728
static constexpr size_t HBUF_OFF = 203474944;   // [2][64 bt][256 j] float2      262,144
static constexpr size_t CST_OFF  = 203737088;   // [2][128][256] f32 c-state     262,144
static constexpr size_t A_OFF    = 203999232;   // [128][5][512] f32           1,310,720
static constexpr size_t PART_OFF = 205309952;   // [128] f32                         512

__device__ __forceinline__ float sigmoidf_(float x) { return 1.f / (1.f + expf(-x)); }
__device__ __forceinline__ float blo_(unsigned u) { return __uint_as_float(u << 16); }
__device__ __forceinline__ float bhi_(unsigned u) { return __uint_as_float(u & 0xffff0000u); }

__device__ __forceinline__ unsigned short f2bf_(float f) {   // RNE bf16
    unsigned u = __float_as_uint(f);
    unsigned r = (u + 0x7fffu + ((u >> 16) & 1u)) >> 16;
    return (unsigned short)r;
}

// ---------------- prep: pack W_hh (bf16, k-pair/gate interleaved) + W_s1^T --
// wbt layout: [(d*128 + k2)*256 + j]*8 + ke*4 + gate  (ushort)
__global__ __launch_bounds__(256) void prep_kernel(const float* __restrict__ Whf,
                                                   const float* __restrict__ Whb,
                                                   const float* __restrict__ Ws1,
                                                   unsigned short* __restrict__ wbt,
                                                   float* __restrict__ ws1t) {
    int idx = blockIdx.x * 256 + threadIdx.x;
    if (idx < 2 * G * H) {
        int d = idx >> 18;
        int rem = idx & 262143;
        int r = rem >> 8;                        // gate row 0..1023
        int k = rem & 255;                       // h index
        const float* W = d ? Whb : Whf;
        int gate = r >> 8, j = r & 255;
        int k2 = k >> 1, ke = k & 1;
        wbt[(((size_t)d * 128 + k2) * 256 + j) * 8 + ke * 4 + gate] = f2bf_(W[(size_t)r * H + k]);
    }
    if (idx < DA * 512) {
        int r = idx / 512, k = idx % 512;
        ws1t[k * DA + r] = Ws1[idx];
    }
}

// ---------------- input projection for one 64-step chunk ----------------
// grid (16 gtiles, 128 b, 2 dir), block 256
__global__ __launch_bounds__(256) void proj_kernel(const int* __restrict__ word_ids,
                                                   const int* __restrict__ lengths,
                                                   const float* __restrict__ emb,
                                                   const float* __restrict__ Wf,
                                                   const float* __restrict__ Wb,
                                                   const float* __restrict__ bf,
                                                   const float* __restrict__ bb,
                                                   float* __restrict__ pxc, int chunk) {
    int g0 = blockIdx.x * 64;
    int b  = blockIdx.y;
    int d  = blockIdx.z;
    int len = lengths[b];
    int t0 = chunk * 64;
    if (t0 >= len) return;
    const float* Wih  = d ? Wb : Wf;
    const float* bias = d ? bb : bf;

    __shared__ int   wid[64];
    __shared__ float As[64][17];   // [m][kk], k-minor, padded
    __shared__ float Bs[64][17];

    int tid = threadIdx.x;
    if (tid < 64) {
        int t = t0 + tid;
        int src;
        if (d == 0) src = t;
        else { src = len - 1 - t; if (src < 0) src = 0; }
        wid[tid] = word_ids[b * T + src];
    }
    __syncthreads();

    int tx = tid & 15, ty = tid >> 4;   // compute mapping
    int kk = tid & 15, r0 = tid >> 4;   // load mapping
    float acc[4][4];
    #pragma unroll
    for (int i = 0; i < 4; i++)
        #pragma unroll
        for (int j = 0; j < 4; j++) acc[i][j] = 0.f;

    for (int k0 = 0; k0 < E; k0 += 16) {
        #pragma unroll
        for (int i = 0; i < 4; i++) {
            int m = r0 + 16 * i;
            As[m][kk] = emb[(size_t)wid[m] * E + k0 + kk];
            Bs[m][kk] = Wih[(size_t)(g0 + m) * E + k0 + kk];
        }
        __syncthreads();
        #pragma unroll
        for (int kq = 0; kq < 16; kq++) {
            float a[4], bv[4];
            #pragma unroll
            for (int i = 0; i < 4; i++) a[i] = As[ty * 4 + i][kq];
            #pragma unroll
            for (int j = 0; j < 4; j++) bv[j] = Bs[tx * 4 + j][kq];
            #pragma unroll
            for (int i = 0; i < 4; i++)
                #pragma unroll
                for (int j = 0; j < 4; j++) acc[i][j] += a[i] * bv[j];
        }
        __syncthreads();
    }
    #pragma unroll
    for (int i = 0; i < 4; i++) {
        int m = ty * 4 + i;
        #pragma unroll
        for (int j = 0; j < 4; j++) {
            int n = tx * 4 + j;
            pxc[((size_t)(d * 64 + m) * B + b) * G + g0 + n] = acc[i][j] + bias[g0 + n];
        }
    }
}

// ---------------- LSTM recurrence, wave-parallel K-split ----------------
// grid (64 btiles, 2 dir); block 1024 = 16 waves. Block owns 2 samples.
// Thread (j = tid&255, kq = tid>>8): partial preacts for hidden col j,
// k-slice [kq*64, kq*64+64), all 4 gates x 2 samples (8 scalar accums, NO
// register arrays). Cross-kq reduction through padded float4 LDS planes.
// W_hh^T bf16 streamed from L2 (512 KB/step/CU); latency hidden by 4 waves/SIMD.
__global__ __launch_bounds__(1024) void lstm4_kernel(const int* __restrict__ lengths,
                                                     const unsigned short* __restrict__ wbt,
                                                     const float* __restrict__ pxc,
                                                     float* __restrict__ hc_out,
                                                     float* __restrict__ hbuf,
                                                     float* __restrict__ cstate,
                                                     int chunk) {
    int bt = blockIdx.x;
    int d  = blockIdx.y;
    int b0 = bt * 2;
    int tid = threadIdx.x;
    int j  = tid & 255;
    int kq = tid >> 8;                 // 0..3 (wave-uniform)

    int len0 = lengths[b0], len1 = lengths[b0 + 1];
    int maxlen = max(len0, len1);
    int t0 = chunk * 64;
    if (t0 >= maxlen) return;
    int tend = min(t0 + 64, maxlen);

    __shared__ float2 hping[2][256];       // [buf][k] = h[k] for {b0, b0+1}
    __shared__ float4 part[3][2][257];     // kq=1..3 partials, padded

    float2* hbufg = (float2*)hbuf + ((size_t)d * 64 + bt) * 256;

    float c0 = 0.f, c1 = 0.f;
    int cur = 0;
    if (chunk == 0) {
        if (tid < 256) hping[0][tid] = make_float2(0.f, 0.f);
    } else if (kq == 0) {
        c0 = cstate[((size_t)d * B + b0) * H + j];
        c1 = cstate[((size_t)d * B + b0 + 1) * H + j];
        hping[0][j] = hbufg[j];
    }
    __syncthreads();

    // thread's W rows: k2 in [kq*32, kq*32+32), column j
    const uint4* wp  = (const uint4*)wbt + (size_t)d * 128 * 256 + (size_t)(kq * 32) * 256 + j;
    const float* pxd = pxc + (size_t)d * 64 * B * G;

    for (int t = t0; t < tend; t++) {
        int s = t - t0;
        // px loads issue here (kq0 waves only), consumed at combine — pipelined
        float p0, p1, p2, p3, p4, p5, p6, p7;
        if (kq == 0) {
            const float* pxs = pxd + ((size_t)s * B + b0) * G;
            p0 = pxs[j];       p1 = pxs[G + j];
            p2 = pxs[256 + j]; p3 = pxs[G + 256 + j];
            p4 = pxs[512 + j]; p5 = pxs[G + 512 + j];
            p6 = pxs[768 + j]; p7 = pxs[G + 768 + j];
        }
        float a00 = 0.f, a01 = 0.f, a10 = 0.f, a11 = 0.f;
        float a20 = 0.f, a21 = 0.f, a30 = 0.f, a31 = 0.f;

        const float4* hcur = (const float4*)hping[cur] + kq * 32;
        #pragma unroll 4
        for (int k2 = 0; k2 < 32; k2++) {
            uint4 wv = wp[(size_t)k2 * 256];
            float4 hv = hcur[k2];          // wave-uniform address -> broadcast
            float w0e = blo_(wv.x), w1e = bhi_(wv.x);
            float w2e = blo_(wv.y), w3e = bhi_(wv.y);
            float w0o = blo_(wv.z), w1o = bhi_(wv.z);
            float w2o = blo_(wv.w), w3o = bhi_(wv.w);
            a00 = fmaf(w0e, hv.x, a00); a01 = fmaf(w0e, hv.y, a01);
            a10 = fmaf(w1e, hv.x, a10); a11 = fmaf(w1e, hv.y, a11);
            a20 = fmaf(w2e, hv.x, a20); a21 = fmaf(w2e, hv.y, a21);
            a30 = fmaf(w3e, hv.x, a30); a31 = fmaf(w3e, hv.y, a31);
            a00 = fmaf(w0o, hv.z, a00); a01 = fmaf(w0o, hv.w, a01);
            a10 = fmaf(w1o, hv.z, a10); a11 = fmaf(w1o, hv.w, a11);
            a20 = fmaf(w2o, hv.z, a20); a21 = fmaf(w2o, hv.w, a21);
            a30 = fmaf(w3o, hv.z, a30); a31 = fmaf(w3o, hv.w, a31);
        }

        if (kq > 0) {
            part[kq - 1][0][j] = make_float4(a00, a01, a10, a11);
            part[kq - 1][1][j] = make_float4(a20, a21, a30, a31);
        }
        __syncthreads();

        if (kq == 0) {
            #pragma unroll
            for (int q = 0; q < 3; q++) {
                float4 q0 = part[q][0][j];
                float4 q1 = part[q][1][j];
                a00 += q0.x; a01 += q0.y; a10 += q0.z; a11 += q0.w;
                a20 += q1.x; a21 += q1.y; a30 += q1.z; a31 += q1.w;
            }
            a00 += p0; a01 += p1; a10 += p2; a11 += p3;
            a20 += p4; a21 += p5; a30 += p6; a31 += p7;

            float i0 = sigmoidf_(a00), f0 = sigmoidf_(a10), o0 = sigmoidf_(a30);
            c0 = f0 * c0 + i0 * tanhf(a20);
            float h0 = o0 * tanhf(c0);
            float i1 = sigmoidf_(a01), f1 = sigmoidf_(a11), o1 = sigmoidf_(a31);
            c1 = f1 * c1 + i1 * tanhf(a21);
            float h1 = o1 * tanhf(c1);

            hping[cur ^ 1][j] = make_float2(h0, h1);
            if (t < len0) {
                int pos = d ? (len0 - 1 - t) : t;
                hc_out[((size_t)b0 * T + pos) * (2 * H) + d * H + j] = h0;
            }
            if (t < len1) {
                int pos = d ? (len1 - 1 - t) : t;
                hc_out[((size_t)(b0 + 1) * T + pos) * (2 * H) + d * H + j] = h1;
            }
        }
        __syncthreads();
        cur ^= 1;
    }

    if (kq == 0) {
        cstate[((size_t)d * B + b0) * H + j]     = c0;
        cstate[((size_t)d * B + b0 + 1) * H + j] = c1;
        hbufg[j] = hping[cur][j];
    }
}

// ---------------- attention logits (masked) ----------------
__global__ __launch_bounds__(256) void logits_kernel(const int* __restrict__ lengths,
                                                     const float* __restrict__ hc,
                                                     const float* __restrict__ ws1t,
                                                     const float* __restrict__ Ws2,
                                                     float* __restrict__ S) {
    __shared__ float s_w1[512 * DA];
    __shared__ float s_w2[HEADS * DA];
    int b = blockIdx.y, tt = blockIdx.x;
    int tid = threadIdx.x;
    for (int i = tid; i < 512 * DA; i += 256) s_w1[i] = ws1t[i];
    for (int i = tid; i < HEADS * DA; i += 256) s_w2[i] = Ws2[i];
    __syncthreads();

    int len = lengths[b];
    int lane = tid & 63, wave = tid >> 6;
    for (int ti = 0; ti < 16; ti++) {
        int t = tt * 64 + wave * 16 + ti;
        if (t < len) {
            float y[DA];
            #pragma unroll
            for (int r = 0; r < DA; r++) y[r] = 0.f;
            const float* hcp = hc + ((size_t)b * T + t) * (2 * H);
            #pragma unroll
            for (int kk = 0; kk < 8; kk++) {
                int k = lane + kk * 64;
                float v = hcp[k];
                const float* w = s_w1 + k * DA;
                #pragma unroll
                for (int r = 0; r < DA; r++) y[r] += v * w[r];
            }
            #pragma unroll
            for (int r = 0; r < DA; r++) {
                float v = y[r];
                for (int off = 32; off; off >>= 1) v += __shfl_xor(v, off, 64);
                y[r] = tanhf(v);
            }
            if (lane < HEADS) {
                float s = 0.f;
                #pragma unroll
                for (int r = 0; r < DA; r++) s += y[r] * s_w2[lane * DA + r];
                S[((size_t)b * HEADS + lane) * T + t] = s;
            }
        } else {
            if (lane < HEADS) S[((size_t)b * HEADS + lane) * T + t] = NEGINF;
        }
    }
}

// ---------------- masked softmax over T, in place ----------------
__global__ __launch_bounds__(256) void softmax_kernel(float* __restrict__ S) {
    int row = blockIdx.x;
    float* p = S + (size_t)row * T;
    int tid = threadIdx.x;
    int lane = tid & 63, wave = tid >> 6;
    __shared__ float rr[4], ss[4];

    float mx = NEGINF;
    #pragma unroll
    for (int i = 0; i < 2; i++) mx = fmaxf(mx, p[tid + i * 256]);
    for (int off = 32; off; off >>= 1) mx = fmaxf(mx, __shfl_xor(mx, off, 64));
    if (lane == 0) rr[wave] = mx;
    __syncthreads();
    mx = fmaxf(fmaxf(rr[0], rr[1]), fmaxf(rr[2], rr[3]));

    float e[2], sum = 0.f;
    #pragma unroll
    for (int i = 0; i < 2; i++) { e[i] = expf(p[tid + i * 256] - mx); sum += e[i]; }
    for (int off = 32; off; off >>= 1) sum += __shfl_xor(sum, off, 64);
    if (lane == 0) ss[wave] = sum;
    __syncthreads();
    sum = ss[0] + ss[1] + ss[2] + ss[3];
    float inv = 1.f / sum;
    #pragma unroll
    for (int i = 0; i < 2; i++) p[tid + i * 256] = e[i] * inv;
}

// ---------------- M = A @ Hc -> sentence embeddings (d_out) ----------------
__global__ __launch_bounds__(256) void attnM_kernel(const int* __restrict__ lengths,
                                                    const float* __restrict__ A,
                                                    const float* __restrict__ hc,
                                                    float* __restrict__ out) {
    int b = blockIdx.x, tid = threadIdx.x;
    int len = lengths[b];
    const float* Ab  = A + (size_t)b * HEADS * T;
    const float* hcb = hc + (size_t)b * T * (2 * H);
    float acc[HEADS][2];
    #pragma unroll
    for (int h = 0; h < HEADS; h++) { acc[h][0] = 0.f; acc[h][1] = 0.f; }
    for (int t = 0; t < len; t++) {
        float v0 = hcb[(size_t)t * (2 * H) + tid];
        float v1 = hcb[(size_t)t * (2 * H) + H + tid];
        #pragma unroll
        for (int h = 0; h < HEADS; h++) {
            float a = Ab[h * T + t];
            acc[h][0] += a * v0;
            acc[h][1] += a * v1;
        }
    }
    #pragma unroll
    for (int h = 0; h < HEADS; h++) {
        out[(size_t)b * (HEADS * 2 * H) + h * (2 * H) + tid]     = acc[h][0];
        out[(size_t)b * (HEADS * 2 * H) + h * (2 * H) + H + tid] = acc[h][1];
    }
}

// ---------------- penalization ----------------
__global__ __launch_bounds__(256) void penal_kernel(const float* __restrict__ A,
                                                    float* __restrict__ part) {
    int b = blockIdx.x, tid = threadIdx.x;
    const float* Ab = A + (size_t)b * HEADS * T;
    float p[10];
    #pragma unroll
    for (int i = 0; i < 10; i++) p[i] = 0.f;
    for (int t = tid; t < T; t += 256) {
        float a0 = Ab[t], a1 = Ab[T + t], a2 = Ab[2 * T + t], a3 = Ab[3 * T + t], a4 = Ab[4 * T + t];
        p[0] += a0 * a1; p[1] += a0 * a2; p[2] += a0 * a3; p[3] += a0 * a4;
        p[4] += a1 * a2; p[5] += a1 * a3; p[6] += a1 * a4;
        p[7] += a2 * a3; p[8] += a2 * a4; p[9] += a3 * a4;
    }
    __shared__ float red[10][4];
    int lane = tid & 63, wave = tid >> 6;
    #pragma unroll
    for (int i = 0; i < 10; i++) {
        float v = p[i];
        for (int off = 32; off; off >>= 1) v += __shfl_xor(v, off, 64);
        if (lane == 0) red[i][wave] = v;
    }
    __syncthreads();
    if (tid == 0) {
        float s = 0.f;
        #pragma unroll
        for (int i = 0; i < 10; i++) {
            float P = red[i][0] + red[i][1] + red[i][2] + red[i][3];
            s += 2.f * P * P;
        }
        part[b] = s;
    }
}

__global__ __launch_bounds__(128) void final_kernel(const float* __restrict__ part,
                                                    float* __restrict__ out) {
    int tid = threadIdx.x;
    float v = part[tid];
    for (int off = 32; off; off >>= 1) v += __shfl_xor(v, off, 64);
    __shared__ float r2[2];
    if ((tid & 63) == 0) r2[tid >> 6] = v;
    __syncthreads();
    if (tid == 0) out[(size_t)B * HEADS * 2 * H] = (r2[0] + r2[1]) * (1.f / (float)B);
}

// ---------------- host launcher ----------------
extern "C" void kernel_launch(void* const* d_in, const int* in_sizes, int n_in,
                              void* d_out, int out_size, void* d_ws, size_t ws_size,
                              hipStream_t stream) {
    const int*   word_ids = (const int*)d_in[0];
    const int*   lengths  = (const int*)d_in[1];
    const float* emb      = (const float*)d_in[2];
    const float* W_ih_f   = (const float*)d_in[3];
    const float* W_hh_f   = (const float*)d_in[4];
    const float* b_f      = (const float*)d_in[5];
    const float* W_ih_b   = (const float*)d_in[6];
    const float* W_hh_b   = (const float*)d_in[7];
    const float* b_b      = (const float*)d_in[8];
    const float* W_s1     = (const float*)d_in[9];
    const float* W_s2     = (const float*)d_in[10];
    float* out = (float*)d_out;

    char* ws = (char*)d_ws;
    unsigned short* wbt = (unsigned short*)(ws + WBT_OFF);
    float* ws1t   = (float*)(ws + WS1T_OFF);
    float* pxc    = (float*)(ws + PX_OFF);
    float* hc     = (float*)(ws + HC_OFF);
    float* hbuf   = (float*)(ws + HBUF_OFF);
    float* cstate = (float*)(ws + CST_OFF);
    float* Abuf   = (float*)(ws + A_OFF);
    float* part   = (float*)(ws + PART_OFF);

    prep_kernel<<<2048, 256, 0, stream>>>(W_hh_f, W_hh_b, W_s1, wbt, ws1t);

    for (int c = 0; c < 8; c++) {
        proj_kernel<<<dim3(16, 128, 2), 256, 0, stream>>>(
            word_ids, lengths, emb, W_ih_f, W_ih_b, b_f, b_b, pxc, c);
        lstm4_kernel<<<dim3(64, 2), 1024, 0, stream>>>(
            lengths, wbt, pxc, hc, hbuf, cstate, c);
    }

    logits_kernel<<<dim3(8, 128), 256, 0, stream>>>(lengths, hc, ws1t, W_s2, Abuf);
    softmax_kernel<<<B * HEADS, 256, 0, stream>>>(Abuf);
    attnM_kernel<<<B, 256, 0, stream>>>(lengths, Abuf, hc, out);
    penal_kernel<<<B, 256, 0, stream>>>(Abuf, part);
    final_kernel<<<1, 128, 0, stream>>>(part, out);
}